// Round 9
// baseline (239.852 us; speedup 1.0000x reference)
//
#include <hip/hip_runtime.h>
#include <math.h>

#define T_STEPS 20

typedef _Float16 half8 __attribute__((ext_vector_type(8)));
typedef float f32x4 __attribute__((ext_vector_type(4)));

// fast transcendentals: v_exp + v_rcp (~1e-7 abs err; threshold is 9.7e-3)
__device__ __forceinline__ float sigm(float v) {
  return __builtin_amdgcn_rcpf(1.0f + __expf(-v));
}
__device__ __forceinline__ float tanh_f(float v) {
  return 1.0f - 2.0f * __builtin_amdgcn_rcpf(1.0f + __expf(2.0f * v));
}

// One block per batch (grid=128; R5: cross-block per-step sync unaffordable).
// 1024 threads = 16 waves, TWO barriers per step (R8 had 4; barrier-phase
// drain was ~half the step time):
//  - waves 0-7 (r = w>>1, csel = w&1): op1 computes ALL 8 gate-chunks for
//    node group r (8 MFMAs, x2 redundant across csel) -> each lane holds all
//    four gates for (hh=n16, n16+16) x nodes 4quad+0..3 in D-frags -> LSTM
//    nonlinearity IN-REGISTER (sgates LDS + its barrier eliminated). Cell
//    state duplicated consistently on the 2 waves per group.
//  - waves 8-15: 3a edge weights (t) + edge prefetch (t+1) concurrently.
//  - B_A: H (cross-group for Q) + w visible.
//  - waves 0-7: P (1 MFMA, bz-init) + own-c Q (4 MFMAs, all groups) ->
//    same-wave LDS transpose (duplicate same-value writes benign) -> op3
//    (2 MFMAs) -> Z writes. Waves 8-15: prefetch only.
//  - B_B: Z visible for next op1.
// Algebra (R8, verified): Z is the recurrent state; gates = Z@(Whh@a2eW)^T +
// folded bias; P=H@(e2aW^T@spaW_a); Q=H@(e2aW^T@spaW_t); Z=tanh(P+Wn@Q+bz);
// classifier folded through a2e. ZERO per-thread arrays (R1/R2: arrays =
// scratch = HBM). MFMA layouts verified m89/R7: A[m=lane&15][k=quad*8+j],
// B[k][n=lane&15] from row-major [n][k], D row=4*quad+reg, col=lane&15.
__global__ __launch_bounds__(1024)
void traj_disc(const float* __restrict__ x, const float* __restrict__ dmat,
               const float* __restrict__ bmat, const float* __restrict__ hmat,
               const float* __restrict__ maskp,
               const float* __restrict__ embW, const float* __restrict__ embb,
               const float* __restrict__ Wih, const float* __restrict__ Whh,
               const float* __restrict__ bih, const float* __restrict__ bhh,
               const float* __restrict__ dom,
               const float* __restrict__ e2aW, const float* __restrict__ e2ab,
               const float* __restrict__ spaW, const float* __restrict__ spab,
               const float* __restrict__ a2eW, const float* __restrict__ a2eb,
               const float* __restrict__ clsW, const float* __restrict__ clsb,
               const float* __restrict__ h0p, const float* __restrict__ c0p,
               float* __restrict__ out)
{
  __shared__ __align__(16) _Float16 sgw[128*40];   // Whh[g][h]        (t=0)
  __shared__ __align__(16) _Float16 sgwc[128*40];  // (Whh@a2eW)[g][k] (t>0)
  __shared__ __align__(16) float4   sgmb[128];     // (M0, M1, b_t0, b_tn)
  __shared__ __align__(16) _Float16 sESaT[32*40];  // (e2aW^T@spaW_a)^T[zk][h]
  __shared__ __align__(16) _Float16 sEStT[32*40];  // (e2aW^T@spaW_t)^T[zk][h]
  __shared__ float bz[32];
  __shared__ float sdom[144];
  __shared__ float sm[1280];                        // mask[b] as [n][t]
  __shared__ float sclsc[32];
  __shared__ float sclsb2[1];
  __shared__ __align__(16) _Float16 sH[64*40];     // h rows f16 (h0 at t=0)
  __shared__ __align__(16) _Float16 sw_[64*72];    // normalized w[i][j] f16
  __shared__ __align__(16) _Float16 sz_[64*40];    // Z rows f16 (recurrent)
  __shared__ __align__(16) _Float16 sQT[32*72];    // Q^T[zk][node] f16

  const int tid = threadIdx.x;
  const int b = blockIdx.x;
  const int w = tid >> 6;     // wave 0..15
  const int l = tid & 63;
  const int quad = l >> 4;
  const int n16 = l & 15;

  // ---- one-time staging (identical folds to R8, verified) ----
  for (int idx = tid; idx < 4096; idx += 1024) sgw[(idx >> 5)*40 + (idx & 31)] = (_Float16)Whh[idx];
  {  // Wcomb[g][k] = Whh@a2eW; 8 threads per g, 4 k each
    const int g = tid >> 3, kb = (tid & 7) << 2;
    float a0 = 0.f, a1 = 0.f, a2 = 0.f, a3 = 0.f;
    #pragma unroll
    for (int h = 0; h < 32; ++h) {
      const float wv = Whh[g*32 + h];
      a0 = fmaf(wv, a2eW[h*32 + kb + 0], a0);
      a1 = fmaf(wv, a2eW[h*32 + kb + 1], a1);
      a2 = fmaf(wv, a2eW[h*32 + kb + 2], a2);
      a3 = fmaf(wv, a2eW[h*32 + kb + 3], a3);
    }
    sgwc[g*40 + kb + 0] = (_Float16)a0; sgwc[g*40 + kb + 1] = (_Float16)a1;
    sgwc[g*40 + kb + 2] = (_Float16)a2; sgwc[g*40 + kb + 3] = (_Float16)a3;
  }
  if (tid < 128) {
    float m0 = 0.f, m1 = 0.f, b0 = bih[tid] + bhh[tid];
    #pragma unroll
    for (int e = 0; e < 16; ++e) {
      float wv_ = Wih[tid*16 + e];
      m0 = fmaf(wv_, embW[2*e],   m0);
      m1 = fmaf(wv_, embW[2*e+1], m1);
      b0 = fmaf(wv_, embb[e],     b0);
    }
    float bn = b0;
    #pragma unroll
    for (int h = 0; h < 32; ++h) bn = fmaf(Whh[tid*32 + h], a2eb[h], bn);
    sgmb[tid] = make_float4(m0, m1, b0, bn);
  }
  {
    const int zk = tid >> 5, hc = tid & 31;
    float sa_ = 0.f, st_ = 0.f;
    #pragma unroll
    for (int a = 0; a < 32; ++a) {
      const float ev = e2aW[a*32 + hc];
      sa_ = fmaf(spaW[zk*64 + a],      ev, sa_);
      st_ = fmaf(spaW[zk*64 + 32 + a], ev, st_);
    }
    sESaT[zk*40 + hc] = (_Float16)sa_;
    sEStT[zk*40 + hc] = (_Float16)st_;
  }
  if (tid < 32) {
    float acc = spab[tid];
    #pragma unroll
    for (int a = 0; a < 32; ++a)
      acc = fmaf(e2ab[a], spaW[tid*64 + a] + spaW[tid*64 + 32 + a], acc);
    bz[tid] = acc;
    float cc = 0.f;
    #pragma unroll
    for (int h = 0; h < 32; ++h) cc = fmaf(clsW[h], a2eW[h*32 + tid], cc);
    sclsc[tid] = cc;
  }
  if (tid == 0) {
    float cb = clsb[0];
    #pragma unroll
    for (int h = 0; h < 32; ++h) cb = fmaf(clsW[h], a2eb[h], cb);
    sclsb2[0] = cb;
  }
  if (tid < 144) sdom[tid] = dom[tid];
  for (int idx = tid; idx < 1280; idx += 1024) sm[idx] = maskp[(size_t)b*1280 + idx];
  for (int idx = tid; idx < 2048; idx += 1024) sH[(idx >> 5)*40 + (idx & 31)] = (_Float16)h0p[(size_t)b*2048 + idx];
  __syncthreads();

  // ---- per-wave persistent registers (divergent init, role-local use) ----
  // waves 0-7: MFMA role
  int r = 0, csel = 0;
  half8 EA = {0}, ET = {0};
  float bzv = 0.f;
  const float* xpre = x;
  float2 xA = {0,0}, xB = {0,0}, xC = {0,0}, xD = {0,0};
  float cA0=0, cA1=0, cA2=0, cA3=0, cB0=0, cB1=0, cB2=0, cB3=0;
  // waves 8-15: edge role
  int i3 = 0, s8 = 0;
  float dm0=0,dm1=0,dm2=0,dm3=0,dm4=0,dm5=0,dm6=0,dm7=0;
  float bm0=0,bm1=0,bm2=0,bm3=0,bm4=0,bm5=0,bm6=0,bm7=0;
  float hm0=0,hm1=0,hm2=0,hm3=0,hm4=0,hm5=0,hm6=0,hm7=0;

  if (w < 8) {
    r = w >> 1; csel = w & 1;
    EA = *(const half8*)(sESaT + (16*csel + n16)*40 + quad*8);
    ET = *(const half8*)(sEStT + (16*csel + n16)*40 + quad*8);
    bzv = bz[16*csel + n16];
    xpre = x + (size_t)(b*64 + 16*r + 4*quad) * 40;
    xA = *(const float2*)(xpre +   0);
    xB = *(const float2*)(xpre +  40);
    xC = *(const float2*)(xpre +  80);
    xD = *(const float2*)(xpre + 120);
    const size_t cb0 = (size_t)(b*64 + 16*r + 4*quad)*32 + n16;
    cA0 = c0p[cb0];        cA1 = c0p[cb0 + 32];
    cA2 = c0p[cb0 + 64];   cA3 = c0p[cb0 + 96];
    cB0 = c0p[cb0 + 16];   cB1 = c0p[cb0 + 48];
    cB2 = c0p[cb0 + 80];   cB3 = c0p[cb0 + 112];
  } else {
    const int t8 = tid - 512;
    i3 = t8 >> 3; s8 = t8 & 7;
    const size_t eb0 = ((size_t)(b*64 + i3)*20 + 0)*64 + s8;
    dm0 = dmat[eb0];      bm0 = bmat[eb0];      hm0 = hmat[eb0];
    dm1 = dmat[eb0 +  8]; bm1 = bmat[eb0 +  8]; hm1 = hmat[eb0 +  8];
    dm2 = dmat[eb0 + 16]; bm2 = bmat[eb0 + 16]; hm2 = hmat[eb0 + 16];
    dm3 = dmat[eb0 + 24]; bm3 = bmat[eb0 + 24]; hm3 = hmat[eb0 + 24];
    dm4 = dmat[eb0 + 32]; bm4 = bmat[eb0 + 32]; hm4 = hmat[eb0 + 32];
    dm5 = dmat[eb0 + 40]; bm5 = bmat[eb0 + 40]; hm5 = hmat[eb0 + 40];
    dm6 = dmat[eb0 + 48]; bm6 = bmat[eb0 + 48]; hm6 = hmat[eb0 + 48];
    dm7 = dmat[eb0 + 56]; bm7 = bmat[eb0 + 56]; hm7 = hmat[eb0 + 56];
  }

  #pragma unroll 1
  for (int t = 0; t < T_STEPS; ++t) {
    if (w < 8) {
      // ---- op1 (8 MFMAs: all gate chunks for node group r) + in-register
      // LSTM nonlinearity + H writes. No barrier before nonlin! ----
      const _Float16* Ab = (t == 0) ? sH : sz_;
      const _Float16* Bb = (t == 0) ? sgw : sgwc;
      const half8 Af = *(const half8*)(Ab + (16*r + n16)*40 + quad*8);
      f32x4 G0, G1, G2, G3, G4, G5, G6, G7;
#define OP1C(c, Gd) { \
      const half8 Bf = *(const half8*)(Bb + (16*(c) + n16)*40 + quad*8); \
      const float4 mb = sgmb[16*(c) + n16]; \
      const float bb = (t == 0) ? mb.z : mb.w; \
      f32x4 Cv; \
      Cv[0] = fmaf(xA.x, mb.x, fmaf(xA.y, mb.y, bb)); \
      Cv[1] = fmaf(xB.x, mb.x, fmaf(xB.y, mb.y, bb)); \
      Cv[2] = fmaf(xC.x, mb.x, fmaf(xC.y, mb.y, bb)); \
      Cv[3] = fmaf(xD.x, mb.x, fmaf(xD.y, mb.y, bb)); \
      Gd = __builtin_amdgcn_mfma_f32_16x16x32_f16(Af, Bf, Cv, 0, 0, 0); }
      OP1C(0, G0) OP1C(1, G1) OP1C(2, G2) OP1C(3, G3)
      OP1C(4, G4) OP1C(5, G5) OP1C(6, G6) OP1C(7, G7)
#undef OP1C
      // gates g=32q+hh: hh=n16 -> chunks 0,2,4,6 ; hh=n16+16 -> 1,3,5,7
#define NL(Gi, Gf, Gg, Go, k, creg, hho) { \
      const float ii = sigm(Gi[k]), ff = sigm(Gf[k]); \
      const float gg = tanh_f(Gg[k]), oo = sigm(Go[k]); \
      creg = fmaf(ff, creg, ii*gg); \
      sH[(16*r + 4*quad + (k))*40 + n16 + (hho)] = (_Float16)(oo * tanh_f(creg)); }
      NL(G0, G2, G4, G6, 0, cA0, 0)  NL(G0, G2, G4, G6, 1, cA1, 0)
      NL(G0, G2, G4, G6, 2, cA2, 0)  NL(G0, G2, G4, G6, 3, cA3, 0)
      NL(G1, G3, G5, G7, 0, cB0, 16) NL(G1, G3, G5, G7, 1, cB1, 16)
      NL(G1, G3, G5, G7, 2, cB2, 16) NL(G1, G3, G5, G7, 3, cB3, 16)
#undef NL
    } else {
      // ---- 3a: normalized edge weights w[i3][j], 8 threads/node ----
      const float mi_ = sm[i3*20 + t];
      float rs = 0.0f;
#define WCOMP(jj) float wn##jj; { \
      int ib_ = (int)floorf(bm##jj * (1.0f/30.0f)); ib_ = ib_ < 0 ? 0 : (ib_ > 11 ? 11 : ib_); \
      int ih_ = (int)floorf(hm##jj * (1.0f/30.0f)); ih_ = ih_ < 0 ? 0 : (ih_ > 11 ? 11 : ih_); \
      float w_ = fmaxf(sdom[ib_*12 + ih_] - dm##jj, 0.0f) * (mi_ * sm[(s8 + 8*(jj))*20 + t]); \
      wn##jj = (s8 + 8*(jj) == i3) ? 0.0f : w_; rs += wn##jj; }
      WCOMP(0) WCOMP(1) WCOMP(2) WCOMP(3) WCOMP(4) WCOMP(5) WCOMP(6) WCOMP(7)
#undef WCOMP
      rs += __shfl_xor(rs, 1); rs += __shfl_xor(rs, 2); rs += __shfl_xor(rs, 4);
      const float inv_ = __builtin_amdgcn_rcpf(rs + 1e-12f);
      sw_[i3*72 + s8 +  0] = (_Float16)(wn0 * inv_);
      sw_[i3*72 + s8 +  8] = (_Float16)(wn1 * inv_);
      sw_[i3*72 + s8 + 16] = (_Float16)(wn2 * inv_);
      sw_[i3*72 + s8 + 24] = (_Float16)(wn3 * inv_);
      sw_[i3*72 + s8 + 32] = (_Float16)(wn4 * inv_);
      sw_[i3*72 + s8 + 40] = (_Float16)(wn5 * inv_);
      sw_[i3*72 + s8 + 48] = (_Float16)(wn6 * inv_);
      sw_[i3*72 + s8 + 56] = (_Float16)(wn7 * inv_);
    }
    __syncthreads();  // B_A: H (all groups) + w visible

    if (w < 8) {
      // ---- P (bz-init) + own-c Q (4 tiles) + same-wave transpose + op3 ----
      const half8 Hr0 = *(const half8*)(sH + (      n16)*40 + quad*8);
      const half8 Hr1 = *(const half8*)(sH + (16  + n16)*40 + quad*8);
      const half8 Hr2 = *(const half8*)(sH + (32  + n16)*40 + quad*8);
      const half8 Hr3 = *(const half8*)(sH + (48  + n16)*40 + quad*8);
      const half8 HrR = (r == 0) ? Hr0 : (r == 1) ? Hr1 : (r == 2) ? Hr2 : Hr3;
      f32x4 Pv = {bzv, bzv, bzv, bzv};
      Pv = __builtin_amdgcn_mfma_f32_16x16x32_f16(HrR, EA, Pv, 0, 0, 0);
#define QT(rq, Afr) { \
      f32x4 Qv = {0.f, 0.f, 0.f, 0.f}; \
      Qv = __builtin_amdgcn_mfma_f32_16x16x32_f16(Afr, ET, Qv, 0, 0, 0); \
      _Float16* qd = sQT + (16*csel + n16)*72 + 16*(rq) + 4*quad; \
      qd[0] = (_Float16)Qv[0]; qd[1] = (_Float16)Qv[1]; \
      qd[2] = (_Float16)Qv[2]; qd[3] = (_Float16)Qv[3]; }
      QT(0, Hr0) QT(1, Hr1) QT(2, Hr2) QT(3, Hr3)
#undef QT
      // same-wave LDS RAW (lgkmcnt, no barrier): read B-frags of own c row
      const half8 A0 = *(const half8*)(sw_ + (16*r + n16)*72 + quad*8);
      const half8 A1 = *(const half8*)(sw_ + (16*r + n16)*72 + 32 + quad*8);
      const half8 B0 = *(const half8*)(sQT + (16*csel + n16)*72 + quad*8);
      const half8 B1 = *(const half8*)(sQT + (16*csel + n16)*72 + 32 + quad*8);
      Pv = __builtin_amdgcn_mfma_f32_16x16x32_f16(A0, B0, Pv, 0, 0, 0);
      Pv = __builtin_amdgcn_mfma_f32_16x16x32_f16(A1, B1, Pv, 0, 0, 0);
      _Float16* zd = sz_ + (16*r + 4*quad)*40 + 16*csel + n16;
      zd[0]   = (_Float16)tanh_f(Pv[0]);
      zd[40]  = (_Float16)tanh_f(Pv[1]);
      zd[80]  = (_Float16)tanh_f(Pv[2]);
      zd[120] = (_Float16)tanh_f(Pv[3]);
      // x prefetch for t+1
      const int tn2 = ((t < T_STEPS - 1) ? t + 1 : t) << 1;
      xA = *(const float2*)(xpre + tn2);
      xB = *(const float2*)(xpre + tn2 +  40);
      xC = *(const float2*)(xpre + tn2 +  80);
      xD = *(const float2*)(xpre + tn2 + 120);
    } else {
      // ---- edge prefetch for t+1 ----
      const int tn = (t < T_STEPS - 1) ? t + 1 : t;
      const size_t ebn = ((size_t)(b*64 + i3)*20 + tn)*64 + s8;
      dm0 = dmat[ebn];      bm0 = bmat[ebn];      hm0 = hmat[ebn];
      dm1 = dmat[ebn +  8]; bm1 = bmat[ebn +  8]; hm1 = hmat[ebn +  8];
      dm2 = dmat[ebn + 16]; bm2 = bmat[ebn + 16]; hm2 = hmat[ebn + 16];
      dm3 = dmat[ebn + 24]; bm3 = bmat[ebn + 24]; hm3 = hmat[ebn + 24];
      dm4 = dmat[ebn + 32]; bm4 = bmat[ebn + 32]; hm4 = hmat[ebn + 32];
      dm5 = dmat[ebn + 40]; bm5 = bmat[ebn + 40]; hm5 = hmat[ebn + 40];
      dm6 = dmat[ebn + 48]; bm6 = bmat[ebn + 48]; hm6 = hmat[ebn + 48];
      dm7 = dmat[ebn + 56]; bm7 = bmat[ebn + 56]; hm7 = hmat[ebn + 56];
    }
    __syncthreads();  // B_B: Z visible for next op1
  }

  // ---- classifier head (folded through a2e, as R8) ----
  if (tid < 64) {
    float acc = sclsb2[0];
    #pragma unroll
    for (int k = 0; k < 32; ++k) acc = fmaf((float)sz_[tid*40 + k], sclsc[k], acc);
    out[(size_t)b*64 + tid] = sigm(tanh_f(acc));
  }
}

extern "C" void kernel_launch(void* const* d_in, const int* in_sizes, int n_in,
                              void* d_out, int out_size, void* d_ws, size_t ws_size,
                              hipStream_t stream) {
  (void)in_sizes; (void)n_in; (void)d_ws; (void)ws_size; (void)out_size;
  const float* x    = (const float*)d_in[0];
  const float* dmat = (const float*)d_in[1];
  const float* bmat = (const float*)d_in[2];
  const float* hmat = (const float*)d_in[3];
  const float* mask = (const float*)d_in[4];
  const float* embW = (const float*)d_in[5];
  const float* embb = (const float*)d_in[6];
  const float* Wih  = (const float*)d_in[7];
  const float* Whh  = (const float*)d_in[8];
  const float* bih  = (const float*)d_in[9];
  const float* bhh  = (const float*)d_in[10];
  const float* dom  = (const float*)d_in[11];
  const float* e2aW = (const float*)d_in[12];
  const float* e2ab = (const float*)d_in[13];
  const float* spaW = (const float*)d_in[14];
  const float* spab = (const float*)d_in[15];
  const float* a2eW = (const float*)d_in[16];
  const float* a2eb = (const float*)d_in[17];
  const float* clsW = (const float*)d_in[18];
  const float* clsb = (const float*)d_in[19];
  const float* h0   = (const float*)d_in[20];
  const float* c0   = (const float*)d_in[21];
  float* out = (float*)d_out;

  traj_disc<<<dim3(128), dim3(1024), 0, stream>>>(
      x, dmat, bmat, hmat, mask, embW, embb, Wih, Whh, bih, bhh, dom,
      e2aW, e2ab, spaW, spab, a2eW, a2eb, clsW, clsb, h0, c0, out);
}

// Round 10
// 238.002 us; speedup vs baseline: 1.0078x; 1.0078x over previous
//
#include <hip/hip_runtime.h>
#include <math.h>

#define T_STEPS 20

typedef _Float16 half8 __attribute__((ext_vector_type(8)));
typedef _Float16 half4v __attribute__((ext_vector_type(4)));
typedef float f32x4 __attribute__((ext_vector_type(4)));

// fast transcendentals: v_exp + v_rcp (~1e-7 abs err; threshold is 9.7e-3)
__device__ __forceinline__ float sigm(float v) {
  return __builtin_amdgcn_rcpf(1.0f + __expf(-v));
}
__device__ __forceinline__ float tanh_f(float v) {
  return 1.0f - 2.0f * __builtin_amdgcn_rcpf(1.0f + __expf(2.0f * v));
}

// ============================================================================
// prep_w: edge weights are recurrence-independent — compute them on ALL 256
// CUs (2560 blocks) instead of inside the 128-block sequential loop. One
// block per (b,t): w[i][j] normalized, f16, laid out so the main kernel can
// read MFMA A-fragments (row = i, k = j) with one 16B load.
// ============================================================================
__global__ __launch_bounds__(256)
void prep_w(const float* __restrict__ dmat, const float* __restrict__ bmat,
            const float* __restrict__ hmat, const float* __restrict__ maskp,
            const float* __restrict__ dom, _Float16* __restrict__ wout)
{
  __shared__ float sdom[144];
  __shared__ float smk[64];
  const int tid = threadIdx.x;
  const int bt = blockIdx.x;            // b*20 + t
  const int b = bt / 20, t = bt - b*20;
  if (tid < 144) sdom[tid] = dom[tid];
  if (tid < 64) smk[tid] = maskp[(size_t)b*1280 + tid*20 + t];
  __syncthreads();
  const int i  = tid >> 2;
  const int jb = (tid & 3) << 4;        // 16 contiguous j per thread
  const size_t eb = ((size_t)(b*64 + i)*20 + t)*64 + jb;
  const float mi = smk[i];
  float rs = 0.f;
#define WC(k) float wv##k; { \
  const float dmv = dmat[eb + (k)]; \
  const float bmv = bmat[eb + (k)]; \
  const float hmv = hmat[eb + (k)]; \
  int ib_ = (int)floorf(bmv * (1.0f/30.0f)); ib_ = ib_ < 0 ? 0 : (ib_ > 11 ? 11 : ib_); \
  int ih_ = (int)floorf(hmv * (1.0f/30.0f)); ih_ = ih_ < 0 ? 0 : (ih_ > 11 ? 11 : ih_); \
  float w_ = fmaxf(sdom[ib_*12 + ih_] - dmv, 0.0f) * (mi * smk[jb + (k)]); \
  wv##k = (jb + (k) == i) ? 0.0f : w_; rs += wv##k; }
  WC(0) WC(1) WC(2) WC(3) WC(4) WC(5) WC(6) WC(7)
  WC(8) WC(9) WC(10) WC(11) WC(12) WC(13) WC(14) WC(15)
#undef WC
  rs += __shfl_xor(rs, 1); rs += __shfl_xor(rs, 2);   // reduce over the 4 j-chunks
  const float inv = __builtin_amdgcn_rcpf(rs + 1e-12f);
  half8 o0, o1;
  o0[0]=(_Float16)(wv0*inv);  o0[1]=(_Float16)(wv1*inv);
  o0[2]=(_Float16)(wv2*inv);  o0[3]=(_Float16)(wv3*inv);
  o0[4]=(_Float16)(wv4*inv);  o0[5]=(_Float16)(wv5*inv);
  o0[6]=(_Float16)(wv6*inv);  o0[7]=(_Float16)(wv7*inv);
  o1[0]=(_Float16)(wv8*inv);  o1[1]=(_Float16)(wv9*inv);
  o1[2]=(_Float16)(wv10*inv); o1[3]=(_Float16)(wv11*inv);
  o1[4]=(_Float16)(wv12*inv); o1[5]=(_Float16)(wv13*inv);
  o1[6]=(_Float16)(wv14*inv); o1[7]=(_Float16)(wv15*inv);
  _Float16* dst = wout + ((size_t)bt*64 + i)*64 + jb;
  *(half8*)(dst)     = o0;
  *(half8*)(dst + 8) = o1;
}

// ============================================================================
// Main sequential kernel: R8 structure (verified 84.9 µs, the best so far;
// R9's role-specialization regressed — keep work symmetric across 16 waves),
// minus ALL edge-weight machinery (3a/sm/sdom/edge regs — now in prep_w).
// w A-frags are global-prefetched one step ahead; ESa/ESt B-frags and bz are
// loop-invariant registers. 4 barriers/step. ZERO per-thread arrays.
// MFMA layouts verified m89/R7: A[m=lane&15][k=quad*8+j]; B[k][n=lane&15]
// from row-major [n][k]; D row=4*quad+reg, col=lane&15.
// ============================================================================
__global__ __launch_bounds__(1024)
void traj_disc_main(const float* __restrict__ x,
                    const float* __restrict__ embW, const float* __restrict__ embb,
                    const float* __restrict__ Wih, const float* __restrict__ Whh,
                    const float* __restrict__ bih, const float* __restrict__ bhh,
                    const float* __restrict__ e2aW, const float* __restrict__ e2ab,
                    const float* __restrict__ spaW, const float* __restrict__ spab,
                    const float* __restrict__ a2eW, const float* __restrict__ a2eb,
                    const float* __restrict__ clsW, const float* __restrict__ clsb,
                    const float* __restrict__ h0p, const float* __restrict__ c0p,
                    const _Float16* __restrict__ wglob,
                    float* __restrict__ out)
{
  __shared__ __align__(16) _Float16 sgw[128*40];   // Whh[g][h]        (t=0)
  __shared__ __align__(16) _Float16 sgwc[128*40];  // (Whh@a2eW)[g][k] (t>0)
  __shared__ __align__(16) float4   sgmb[128];     // (M0, M1, b_t0, b_tn)
  __shared__ __align__(16) _Float16 sESaT[32*40];  // (e2aW^T@spaW_a)^T[zk][h]
  __shared__ __align__(16) _Float16 sEStT[32*40];  // (e2aW^T@spaW_t)^T[zk][h]
  __shared__ float bz[32];
  __shared__ float sclsc[32];
  __shared__ float sclsb2[1];
  __shared__ __align__(16) _Float16 sH[64*40];     // h rows f16 (h0 at t=0)
  __shared__ __align__(16) _Float16 sz_[64*40];    // Z rows f16 (recurrent)
  __shared__ __align__(16) _Float16 sQT[32*72];    // Q^T[zk][node] f16
  __shared__ __align__(16) float sgates[128*68];   // gates[gate][node] f32

  const int tid = threadIdx.x;
  const int b = blockIdx.x;
  const int i = tid >> 4;     // node (nonlin decomposition)
  const int s = tid & 15;
  const int w = tid >> 6;     // wave 0..15
  const int l = tid & 63;
  const int quad = l >> 4;
  const int n16 = l & 15;

  // ---- one-time staging (folds identical to R8, verified) ----
  for (int idx = tid; idx < 4096; idx += 1024) sgw[(idx >> 5)*40 + (idx & 31)] = (_Float16)Whh[idx];
  {  // Wcomb[g][k] = Whh@a2eW; 8 threads per g, 4 k each
    const int g = tid >> 3, kb = (tid & 7) << 2;
    float a0 = 0.f, a1 = 0.f, a2 = 0.f, a3 = 0.f;
    #pragma unroll
    for (int h = 0; h < 32; ++h) {
      const float wv = Whh[g*32 + h];
      a0 = fmaf(wv, a2eW[h*32 + kb + 0], a0);
      a1 = fmaf(wv, a2eW[h*32 + kb + 1], a1);
      a2 = fmaf(wv, a2eW[h*32 + kb + 2], a2);
      a3 = fmaf(wv, a2eW[h*32 + kb + 3], a3);
    }
    sgwc[g*40 + kb + 0] = (_Float16)a0; sgwc[g*40 + kb + 1] = (_Float16)a1;
    sgwc[g*40 + kb + 2] = (_Float16)a2; sgwc[g*40 + kb + 3] = (_Float16)a3;
  }
  if (tid < 128) {
    float m0 = 0.f, m1 = 0.f, b0 = bih[tid] + bhh[tid];
    #pragma unroll
    for (int e = 0; e < 16; ++e) {
      float wv_ = Wih[tid*16 + e];
      m0 = fmaf(wv_, embW[2*e],   m0);
      m1 = fmaf(wv_, embW[2*e+1], m1);
      b0 = fmaf(wv_, embb[e],     b0);
    }
    float bn = b0;
    #pragma unroll
    for (int h = 0; h < 32; ++h) bn = fmaf(Whh[tid*32 + h], a2eb[h], bn);
    sgmb[tid] = make_float4(m0, m1, b0, bn);
  }
  {
    const int zk = tid >> 5, hc = tid & 31;
    float sa_ = 0.f, st_ = 0.f;
    #pragma unroll
    for (int a = 0; a < 32; ++a) {
      const float ev = e2aW[a*32 + hc];
      sa_ = fmaf(spaW[zk*64 + a],      ev, sa_);
      st_ = fmaf(spaW[zk*64 + 32 + a], ev, st_);
    }
    sESaT[zk*40 + hc] = (_Float16)sa_;
    sEStT[zk*40 + hc] = (_Float16)st_;
  }
  if (tid < 32) {
    float acc = spab[tid];
    #pragma unroll
    for (int a = 0; a < 32; ++a)
      acc = fmaf(e2ab[a], spaW[tid*64 + a] + spaW[tid*64 + 32 + a], acc);
    bz[tid] = acc;
    float cc = 0.f;
    #pragma unroll
    for (int h = 0; h < 32; ++h) cc = fmaf(clsW[h], a2eW[h*32 + tid], cc);
    sclsc[tid] = cc;
  }
  if (tid == 0) {
    float cb = clsb[0];
    #pragma unroll
    for (int h = 0; h < 32; ++h) cb = fmaf(clsW[h], a2eb[h], cb);
    sclsb2[0] = cb;
  }
  for (int idx = tid; idx < 2048; idx += 1024) sH[(idx >> 5)*40 + (idx & 31)] = (_Float16)h0p[(size_t)b*2048 + idx];
  float c0r = c0p[(size_t)b*2048 + i*32 + s];       // cell f32, hh = s
  float c1r = c0p[(size_t)b*2048 + i*32 + s + 16];  // cell f32, hh = s+16
  __syncthreads();

  // ---- loop-invariant registers ----
  const float* xpre = x + (size_t)(b*64 + ((w >> 2) << 4) + (quad << 2)) * 40;
  float2 xA = *(const float2*)(xpre +   0);
  float2 xB = *(const float2*)(xpre +  40);
  float2 xC = *(const float2*)(xpre +  80);
  float2 xD = *(const float2*)(xpre + 120);
  // op2 B-frag + bias: waves 0-7 use ESa (c = w&1), waves 8-15 ESt (c = (w-8)&1)
  half8 Bconst;
  float bzv = 0.f;
  half8 wA0 = {0}, wA1 = {0};   // op3 A-frags (waves 0-7), prefetched per step
  if (w < 8) {
    const int c = w & 1, r = w >> 1;
    Bconst = *(const half8*)(sESaT + (16*c + n16)*40 + quad*8);
    bzv = bz[16*c + n16];
    const _Float16* wp = wglob + ((size_t)(b*20 + 0)*64 + 16*r + n16)*64 + quad*8;
    wA0 = *(const half8*)(wp);
    wA1 = *(const half8*)(wp + 32);
  } else {
    const int c = (w - 8) & 1;
    Bconst = *(const half8*)(sEStT + (16*c + n16)*40 + quad*8);
  }

  #pragma unroll 1
  for (int t = 0; t < T_STEPS; ++t) {
    // ---- op1: Gates = State @ W^T + x-part (16 waves x 2 chunk-tiles) ----
    {
      const int r1 = w >> 2, cp = (w & 3) << 1;
      const _Float16* Ab = (t == 0) ? sH : sz_;
      const _Float16* Bb = (t == 0) ? sgw : sgwc;
      const half8 Af = *(const half8*)(Ab + (16*r1 + n16)*40 + quad*8);
#define OP1C(c) { \
      const half8 Bf = *(const half8*)(Bb + (16*(c) + n16)*40 + quad*8); \
      const float4 mb = sgmb[16*(c) + n16]; \
      const float bb = (t == 0) ? mb.z : mb.w; \
      f32x4 Cv; \
      Cv[0] = fmaf(xA.x, mb.x, fmaf(xA.y, mb.y, bb)); \
      Cv[1] = fmaf(xB.x, mb.x, fmaf(xB.y, mb.y, bb)); \
      Cv[2] = fmaf(xC.x, mb.x, fmaf(xC.y, mb.y, bb)); \
      Cv[3] = fmaf(xD.x, mb.x, fmaf(xD.y, mb.y, bb)); \
      Cv = __builtin_amdgcn_mfma_f32_16x16x32_f16(Af, Bf, Cv, 0, 0, 0); \
      *(f32x4*)(sgates + (16*(c) + n16)*68 + 16*r1 + 4*quad) = Cv; }
      OP1C(cp) OP1C(cp + 1)
#undef OP1C
    }
    // x prefetch for t+1 (x(t) fully consumed by op1 above)
    {
      const int tn2 = ((t < T_STEPS - 1) ? t + 1 : t) << 1;
      xA = *(const float2*)(xpre + tn2);
      xB = *(const float2*)(xpre + tn2 +  40);
      xC = *(const float2*)(xpre + tn2 +  80);
      xD = *(const float2*)(xpre + tn2 + 120);
    }
    __syncthreads();  // B1: gates visible

    // ---- nonlin: LSTM cell per (i, hh = s + 16u); c stays in this lane ----
    {
#define GR(q, u) sgates[((q)*32 + s + 16*(u))*68 + i]
      const float ai0 = GR(0,0), af0 = GR(1,0), ag0 = GR(2,0), ao0 = GR(3,0);
      const float ai1 = GR(0,1), af1 = GR(1,1), ag1 = GR(2,1), ao1 = GR(3,1);
#undef GR
      c0r = fmaf(sigm(af0), c0r, sigm(ai0)*tanh_f(ag0));
      sH[i*40 + s]      = (_Float16)(sigm(ao0)*tanh_f(c0r));
      c1r = fmaf(sigm(af1), c1r, sigm(ai1)*tanh_f(ag1));
      sH[i*40 + s + 16] = (_Float16)(sigm(ao1)*tanh_f(c1r));
    }
    __syncthreads();  // B2: h visible

    // ---- op2: waves 0-7 P = H@ESa + bz (REGISTERS); waves 8-15 Q -> sQT ----
    f32x4 Pv = {0.f, 0.f, 0.f, 0.f};
    if (w < 8) {
      const int r = w >> 1;
      const half8 Af = *(const half8*)(sH + (16*r + n16)*40 + quad*8);
      Pv[0] = bzv; Pv[1] = bzv; Pv[2] = bzv; Pv[3] = bzv;
      Pv = __builtin_amdgcn_mfma_f32_16x16x32_f16(Af, Bconst, Pv, 0, 0, 0);
    } else {
      const int w8 = w - 8, r = w8 >> 1, c = w8 & 1;
      const half8 Af = *(const half8*)(sH + (16*r + n16)*40 + quad*8);
      f32x4 Cv = {0.f, 0.f, 0.f, 0.f};
      Cv = __builtin_amdgcn_mfma_f32_16x16x32_f16(Af, Bconst, Cv, 0, 0, 0);
      half4v hq;
      hq[0] = (_Float16)Cv[0]; hq[1] = (_Float16)Cv[1];
      hq[2] = (_Float16)Cv[2]; hq[3] = (_Float16)Cv[3];
      *(half4v*)(sQT + (16*c + n16)*72 + 16*r + 4*quad) = hq;
    }
    __syncthreads();  // B3: Q^T visible (P rides in registers)

    // ---- op3: Z = tanh(Pv + Wn@Q) (waves 0-7, w A-frags prefetched) ----
    if (w < 8) {
      const int r = w >> 1, c = w & 1;
      const half8 B0 = *(const half8*)(sQT + (16*c + n16)*72 + quad*8);
      const half8 B1 = *(const half8*)(sQT + (16*c + n16)*72 + 32 + quad*8);
      Pv = __builtin_amdgcn_mfma_f32_16x16x32_f16(wA0, B0, Pv, 0, 0, 0);
      Pv = __builtin_amdgcn_mfma_f32_16x16x32_f16(wA1, B1, Pv, 0, 0, 0);
      _Float16* zd = sz_ + (16*r + 4*quad)*40 + 16*c + n16;
      zd[0]   = (_Float16)tanh_f(Pv[0]);
      zd[40]  = (_Float16)tanh_f(Pv[1]);
      zd[80]  = (_Float16)tanh_f(Pv[2]);
      zd[120] = (_Float16)tanh_f(Pv[3]);
      // prefetch w A-frags for t+1 (full step of latency cover, L2/L3-hit)
      const int tn = (t < T_STEPS - 1) ? t + 1 : t;
      const _Float16* wp = wglob + ((size_t)(b*20 + tn)*64 + 16*r + n16)*64 + quad*8;
      wA0 = *(const half8*)(wp);
      wA1 = *(const half8*)(wp + 32);
    }
    __syncthreads();  // B4: Z visible for next op1
  }

  // ---- classifier head (folded through a2e) ----
  if (tid < 64) {
    float acc = sclsb2[0];
    #pragma unroll
    for (int k = 0; k < 32; ++k) acc = fmaf((float)sz_[tid*40 + k], sclsc[k], acc);
    out[(size_t)b*64 + tid] = sigm(tanh_f(acc));
  }
}

// ============================================================================
// Fallback: R8 kernel verbatim (verified 84.9 µs, absmax 1.95e-3) — used only
// if ws_size cannot hold the 20 MB precomputed-w buffer.
// ============================================================================
__global__ __launch_bounds__(1024)
void traj_disc_fb(const float* __restrict__ x, const float* __restrict__ dmat,
                  const float* __restrict__ bmat, const float* __restrict__ hmat,
                  const float* __restrict__ maskp,
                  const float* __restrict__ embW, const float* __restrict__ embb,
                  const float* __restrict__ Wih, const float* __restrict__ Whh,
                  const float* __restrict__ bih, const float* __restrict__ bhh,
                  const float* __restrict__ dom,
                  const float* __restrict__ e2aW, const float* __restrict__ e2ab,
                  const float* __restrict__ spaW, const float* __restrict__ spab,
                  const float* __restrict__ a2eW, const float* __restrict__ a2eb,
                  const float* __restrict__ clsW, const float* __restrict__ clsb,
                  const float* __restrict__ h0p, const float* __restrict__ c0p,
                  float* __restrict__ out)
{
  __shared__ __align__(16) _Float16 sgw[128*40];
  __shared__ __align__(16) _Float16 sgwc[128*40];
  __shared__ __align__(16) float4   sgmb[128];
  __shared__ __align__(16) _Float16 sESaT[32*40];
  __shared__ __align__(16) _Float16 sEStT[32*40];
  __shared__ float bz[32];
  __shared__ float sdom[144];
  __shared__ float sm[1280];
  __shared__ float sclsc[32];
  __shared__ float sclsb2[1];
  __shared__ __align__(16) _Float16 sH[64*40];
  __shared__ __align__(16) _Float16 sw_[64*72];
  __shared__ __align__(16) _Float16 sz_[64*40];
  __shared__ __align__(16) _Float16 sQT[32*72];
  __shared__ __align__(16) float sgates[128*68];

  const int tid = threadIdx.x;
  const int b = blockIdx.x;
  const int i = tid >> 4;
  const int s = tid & 15;
  const int w = tid >> 6;
  const int l = tid & 63;
  const int quad = l >> 4;
  const int n16 = l & 15;

  for (int idx = tid; idx < 4096; idx += 1024) sgw[(idx >> 5)*40 + (idx & 31)] = (_Float16)Whh[idx];
  {
    const int g = tid >> 3, kb = (tid & 7) << 2;
    float a0 = 0.f, a1 = 0.f, a2 = 0.f, a3 = 0.f;
    #pragma unroll
    for (int h = 0; h < 32; ++h) {
      const float wv = Whh[g*32 + h];
      a0 = fmaf(wv, a2eW[h*32 + kb + 0], a0);
      a1 = fmaf(wv, a2eW[h*32 + kb + 1], a1);
      a2 = fmaf(wv, a2eW[h*32 + kb + 2], a2);
      a3 = fmaf(wv, a2eW[h*32 + kb + 3], a3);
    }
    sgwc[g*40 + kb + 0] = (_Float16)a0; sgwc[g*40 + kb + 1] = (_Float16)a1;
    sgwc[g*40 + kb + 2] = (_Float16)a2; sgwc[g*40 + kb + 3] = (_Float16)a3;
  }
  if (tid < 128) {
    float m0 = 0.f, m1 = 0.f, b0 = bih[tid] + bhh[tid];
    #pragma unroll
    for (int e = 0; e < 16; ++e) {
      float wv_ = Wih[tid*16 + e];
      m0 = fmaf(wv_, embW[2*e],   m0);
      m1 = fmaf(wv_, embW[2*e+1], m1);
      b0 = fmaf(wv_, embb[e],     b0);
    }
    float bn = b0;
    #pragma unroll
    for (int h = 0; h < 32; ++h) bn = fmaf(Whh[tid*32 + h], a2eb[h], bn);
    sgmb[tid] = make_float4(m0, m1, b0, bn);
  }
  {
    const int zk = tid >> 5, hc = tid & 31;
    float sa_ = 0.f, st_ = 0.f;
    #pragma unroll
    for (int a = 0; a < 32; ++a) {
      const float ev = e2aW[a*32 + hc];
      sa_ = fmaf(spaW[zk*64 + a],      ev, sa_);
      st_ = fmaf(spaW[zk*64 + 32 + a], ev, st_);
    }
    sESaT[zk*40 + hc] = (_Float16)sa_;
    sEStT[zk*40 + hc] = (_Float16)st_;
  }
  if (tid < 32) {
    float acc = spab[tid];
    #pragma unroll
    for (int a = 0; a < 32; ++a)
      acc = fmaf(e2ab[a], spaW[tid*64 + a] + spaW[tid*64 + 32 + a], acc);
    bz[tid] = acc;
    float cc = 0.f;
    #pragma unroll
    for (int h = 0; h < 32; ++h) cc = fmaf(clsW[h], a2eW[h*32 + tid], cc);
    sclsc[tid] = cc;
  }
  if (tid == 0) {
    float cb = clsb[0];
    #pragma unroll
    for (int h = 0; h < 32; ++h) cb = fmaf(clsW[h], a2eb[h], cb);
    sclsb2[0] = cb;
  }
  if (tid < 144) sdom[tid] = dom[tid];
  for (int idx = tid; idx < 1280; idx += 1024) sm[idx] = maskp[(size_t)b*1280 + idx];
  for (int idx = tid; idx < 2048; idx += 1024) sH[(idx >> 5)*40 + (idx & 31)] = (_Float16)h0p[(size_t)b*2048 + idx];
  float c0r = c0p[(size_t)b*2048 + i*32 + s];
  float c1r = c0p[(size_t)b*2048 + i*32 + s + 16];
  __syncthreads();

  const size_t nb = (size_t)b*64 + i;
  const float* xpre = x + (size_t)(b*64 + ((w >> 2) << 4) + (quad << 2)) * 40;
  float2 xA = *(const float2*)(xpre +   0);
  float2 xB = *(const float2*)(xpre +  40);
  float2 xC = *(const float2*)(xpre +  80);
  float2 xD = *(const float2*)(xpre + 120);
  size_t eb_ = nb*1280;
  float dm0 = dmat[eb_ + s],      bm0 = bmat[eb_ + s],      hm0 = hmat[eb_ + s];
  float dm1 = dmat[eb_ + s + 16], bm1 = bmat[eb_ + s + 16], hm1 = hmat[eb_ + s + 16];
  float dm2 = dmat[eb_ + s + 32], bm2 = bmat[eb_ + s + 32], hm2 = hmat[eb_ + s + 32];
  float dm3 = dmat[eb_ + s + 48], bm3 = bmat[eb_ + s + 48], hm3 = hmat[eb_ + s + 48];

  #pragma unroll 1
  for (int t = 0; t < T_STEPS; ++t) {
    {
      const int r1 = w >> 2, cp = (w & 3) << 1;
      const _Float16* Ab = (t == 0) ? sH : sz_;
      const _Float16* Bb = (t == 0) ? sgw : sgwc;
      const half8 Af = *(const half8*)(Ab + (16*r1 + n16)*40 + quad*8);
#define OP1C(c) { \
      const half8 Bf = *(const half8*)(Bb + (16*(c) + n16)*40 + quad*8); \
      const float4 mb = sgmb[16*(c) + n16]; \
      const float bb = (t == 0) ? mb.z : mb.w; \
      f32x4 Cv; \
      Cv[0] = fmaf(xA.x, mb.x, fmaf(xA.y, mb.y, bb)); \
      Cv[1] = fmaf(xB.x, mb.x, fmaf(xB.y, mb.y, bb)); \
      Cv[2] = fmaf(xC.x, mb.x, fmaf(xC.y, mb.y, bb)); \
      Cv[3] = fmaf(xD.x, mb.x, fmaf(xD.y, mb.y, bb)); \
      Cv = __builtin_amdgcn_mfma_f32_16x16x32_f16(Af, Bf, Cv, 0, 0, 0); \
      *(f32x4*)(sgates + (16*(c) + n16)*68 + 16*r1 + 4*quad) = Cv; }
      OP1C(cp) OP1C(cp + 1)
#undef OP1C
    }
    __syncthreads();
    {
#define GR(q, u) sgates[((q)*32 + s + 16*(u))*68 + i]
      const float ai0 = GR(0,0), af0 = GR(1,0), ag0 = GR(2,0), ao0 = GR(3,0);
      const float ai1 = GR(0,1), af1 = GR(1,1), ag1 = GR(2,1), ao1 = GR(3,1);
#undef GR
      c0r = fmaf(sigm(af0), c0r, sigm(ai0)*tanh_f(ag0));
      sH[i*40 + s]      = (_Float16)(sigm(ao0)*tanh_f(c0r));
      c1r = fmaf(sigm(af1), c1r, sigm(ai1)*tanh_f(ag1));
      sH[i*40 + s + 16] = (_Float16)(sigm(ao1)*tanh_f(c1r));
    }
    {
      const float mi_ = sm[i*20 + t];
      float rs = 0.0f;
#define WCOMP(jj) float wn##jj; { \
      int ib_ = (int)floorf(bm##jj * (1.0f/30.0f)); ib_ = ib_ < 0 ? 0 : (ib_ > 11 ? 11 : ib_); \
      int ih_ = (int)floorf(hm##jj * (1.0f/30.0f)); ih_ = ih_ < 0 ? 0 : (ih_ > 11 ? 11 : ih_); \
      float w_ = fmaxf(sdom[ib_*12 + ih_] - dm##jj, 0.0f) * (mi_ * sm[(s + 16*(jj))*20 + t]); \
      wn##jj = (s + 16*(jj) == i) ? 0.0f : w_; rs += wn##jj; }
      WCOMP(0) WCOMP(1) WCOMP(2) WCOMP(3)
#undef WCOMP
      rs += __shfl_xor(rs, 1); rs += __shfl_xor(rs, 2);
      rs += __shfl_xor(rs, 4); rs += __shfl_xor(rs, 8);
      const float inv_ = __builtin_amdgcn_rcpf(rs + 1e-12f);
      sw_[i*72 + s +  0] = (_Float16)(wn0 * inv_);
      sw_[i*72 + s + 16] = (_Float16)(wn1 * inv_);
      sw_[i*72 + s + 32] = (_Float16)(wn2 * inv_);
      sw_[i*72 + s + 48] = (_Float16)(wn3 * inv_);
    }
    {
      const int tn = (t < T_STEPS - 1) ? t + 1 : t;
      const size_t ebn = (nb*20 + tn)*64;
      dm0 = dmat[ebn + s];      bm0 = bmat[ebn + s];      hm0 = hmat[ebn + s];
      dm1 = dmat[ebn + s + 16]; bm1 = bmat[ebn + s + 16]; hm1 = hmat[ebn + s + 16];
      dm2 = dmat[ebn + s + 32]; bm2 = bmat[ebn + s + 32]; hm2 = hmat[ebn + s + 32];
      dm3 = dmat[ebn + s + 48]; bm3 = bmat[ebn + s + 48]; hm3 = hmat[ebn + s + 48];
      const int tn2 = tn << 1;
      xA = *(const float2*)(xpre + tn2);
      xB = *(const float2*)(xpre + tn2 +  40);
      xC = *(const float2*)(xpre + tn2 +  80);
      xD = *(const float2*)(xpre + tn2 + 120);
    }
    __syncthreads();
    f32x4 Pv = {0.f, 0.f, 0.f, 0.f};
    if (w < 8) {
      const int r = w >> 1, c = w & 1;
      const half8 Af = *(const half8*)(sH    + (16*r + n16)*40 + quad*8);
      const half8 Bf = *(const half8*)(sESaT + (16*c + n16)*40 + quad*8);
      const float bzv = bz[16*c + n16];
      Pv[0] = bzv; Pv[1] = bzv; Pv[2] = bzv; Pv[3] = bzv;
      Pv = __builtin_amdgcn_mfma_f32_16x16x32_f16(Af, Bf, Pv, 0, 0, 0);
    } else {
      const int w8 = w - 8, r = w8 >> 1, c = w8 & 1;
      const half8 Af = *(const half8*)(sH    + (16*r + n16)*40 + quad*8);
      const half8 Bf = *(const half8*)(sEStT + (16*c + n16)*40 + quad*8);
      f32x4 Cv = {0.f, 0.f, 0.f, 0.f};
      Cv = __builtin_amdgcn_mfma_f32_16x16x32_f16(Af, Bf, Cv, 0, 0, 0);
      half4v hq;
      hq[0] = (_Float16)Cv[0]; hq[1] = (_Float16)Cv[1];
      hq[2] = (_Float16)Cv[2]; hq[3] = (_Float16)Cv[3];
      *(half4v*)(sQT + (16*c + n16)*72 + 16*r + 4*quad) = hq;
    }
    __syncthreads();
    if (w < 8) {
      const int r = w >> 1, c = w & 1;
      const half8 A0 = *(const half8*)(sw_ + (16*r + n16)*72 + quad*8);
      const half8 A1 = *(const half8*)(sw_ + (16*r + n16)*72 + 32 + quad*8);
      const half8 B0 = *(const half8*)(sQT + (16*c + n16)*72 + quad*8);
      const half8 B1 = *(const half8*)(sQT + (16*c + n16)*72 + 32 + quad*8);
      Pv = __builtin_amdgcn_mfma_f32_16x16x32_f16(A0, B0, Pv, 0, 0, 0);
      Pv = __builtin_amdgcn_mfma_f32_16x16x32_f16(A1, B1, Pv, 0, 0, 0);
      _Float16* zd = sz_ + (16*r + 4*quad)*40 + 16*c + n16;
      zd[0]   = (_Float16)tanh_f(Pv[0]);
      zd[40]  = (_Float16)tanh_f(Pv[1]);
      zd[80]  = (_Float16)tanh_f(Pv[2]);
      zd[120] = (_Float16)tanh_f(Pv[3]);
    }
    __syncthreads();
  }

  if (tid < 64) {
    float acc = sclsb2[0];
    #pragma unroll
    for (int k = 0; k < 32; ++k) acc = fmaf((float)sz_[tid*40 + k], sclsc[k], acc);
    out[(size_t)b*64 + tid] = sigm(tanh_f(acc));
  }
}

extern "C" void kernel_launch(void* const* d_in, const int* in_sizes, int n_in,
                              void* d_out, int out_size, void* d_ws, size_t ws_size,
                              hipStream_t stream) {
  (void)in_sizes; (void)n_in; (void)out_size;
  const float* x    = (const float*)d_in[0];
  const float* dmat = (const float*)d_in[1];
  const float* bmat = (const float*)d_in[2];
  const float* hmat = (const float*)d_in[3];
  const float* mask = (const float*)d_in[4];
  const float* embW = (const float*)d_in[5];
  const float* embb = (const float*)d_in[6];
  const float* Wih  = (const float*)d_in[7];
  const float* Whh  = (const float*)d_in[8];
  const float* bih  = (const float*)d_in[9];
  const float* bhh  = (const float*)d_in[10];
  const float* dom  = (const float*)d_in[11];
  const float* e2aW = (const float*)d_in[12];
  const float* e2ab = (const float*)d_in[13];
  const float* spaW = (const float*)d_in[14];
  const float* spab = (const float*)d_in[15];
  const float* a2eW = (const float*)d_in[16];
  const float* a2eb = (const float*)d_in[17];
  const float* clsW = (const float*)d_in[18];
  const float* clsb = (const float*)d_in[19];
  const float* h0   = (const float*)d_in[20];
  const float* c0   = (const float*)d_in[21];
  float* out = (float*)d_out;

  const size_t WNEED = (size_t)128 * 20 * 64 * 64 * sizeof(_Float16);  // 20 MB
  if (ws_size >= WNEED) {
    _Float16* wbuf = (_Float16*)d_ws;
    prep_w<<<dim3(128*20), dim3(256), 0, stream>>>(dmat, bmat, hmat, mask, dom, wbuf);
    traj_disc_main<<<dim3(128), dim3(1024), 0, stream>>>(
        x, embW, embb, Wih, Whh, bih, bhh, e2aW, e2ab, spaW, spab,
        a2eW, a2eb, clsW, clsb, h0, c0, wbuf, out);
  } else {
    traj_disc_fb<<<dim3(128), dim3(1024), 0, stream>>>(
        x, dmat, bmat, hmat, mask, embW, embb, Wih, Whh, bih, bhh, dom,
        e2aW, e2ab, spaW, spab, a2eW, a2eb, clsW, clsb, h0, c0, out);
  }
}